// Round 6
// baseline (295.076 us; speedup 1.0000x reference)
//
#include <hip/hip_runtime.h>
#include <hip/hip_bf16.h>
#include <math.h>

typedef __attribute__((ext_vector_type(8))) short bf16x8;
typedef __attribute__((ext_vector_type(4))) short bf16x4;
typedef __attribute__((ext_vector_type(4))) float floatx4;
typedef __attribute__((ext_vector_type(4))) unsigned int uint4v;

constexpr int kN  = 4096;
constexpr int kD  = 768;
constexpr int kH  = 12;
constexpr int kHD = 64;
constexpr int k3D = 2304;
// Q pre-scale: (1/sqrt(64)) * log2(e) so softmax runs in exp2 domain with no muls
constexpr float kQScale = 0.18033688011112042f;

static __device__ __forceinline__ short f2b(float f) {
    __hip_bfloat16 h = __float2bfloat16(f);
    return *reinterpret_cast<short*>(&h);
}

static __device__ __forceinline__ float fast_exp2(float x) {
#if __has_builtin(__builtin_amdgcn_exp2f)
    return __builtin_amdgcn_exp2f(x);
#else
    return exp2f(x);
#endif
}

// v_cvt_pk_bf16_f32: pack two f32 -> one dword of 2 bf16 (lo, hi)
static __device__ __forceinline__ unsigned cvt_pk_bf16(float lo, float hi) {
    unsigned r;
    asm("v_cvt_pk_bf16_f32 %0, %1, %2" : "=v"(r) : "v"(lo), "v"(hi));
    return r;
}
// permlane swaps (gfx950): both operands read-modify-write.
static __device__ __forceinline__ void permlane32_swap(unsigned &a, unsigned &b) {
    asm("v_permlane32_swap_b32 %0, %1" : "+v"(a), "+v"(b));
}
static __device__ __forceinline__ void permlane16_swap(unsigned &a, unsigned &b) {
    asm("v_permlane16_swap_b32 %0, %1" : "+v"(a), "+v"(b));
}

// Async global->LDS DMA, 16B per lane. LDS dst is wave-uniform base + lane*16.
static __device__ __forceinline__ void async_copy16(const void* g, void* l) {
    __builtin_amdgcn_global_load_lds(
        (const __attribute__((address_space(1))) void*)g,
        (__attribute__((address_space(3))) void*)l, 16, 0, 0);
}

// Fused prep: section 0 = x fp32->bf16; section 1 = W_qkv transpose->bf16;
// section 2 = W_out transpose->bf16. One launch instead of three.
constexpr int kBlkX  = 1536;            // (4096*768/8)/256
constexpr int kBlkWq = 72 * 24;         // (2304/32) x (768/32)
constexpr int kBlkWo = 24 * 24;         // (768/32) x (768/32)

__global__ __launch_bounds__(256)
void prep(const float* __restrict__ x, const float* __restrict__ Wq,
          const float* __restrict__ Wo, short* __restrict__ Xb,
          short* __restrict__ WqT, short* __restrict__ WoT)
{
    const int bid = blockIdx.x;
    const int tid = threadIdx.x;
    if (bid < kBlkX) {
        const int i = bid * 256 + tid;
        const float4* s = reinterpret_cast<const float4*>(x + (size_t)i * 8);
        float4 a = s[0], b = s[1];
        bf16x8 v;
        v[0] = f2b(a.x); v[1] = f2b(a.y); v[2] = f2b(a.z); v[3] = f2b(a.w);
        v[4] = f2b(b.x); v[5] = f2b(b.y); v[6] = f2b(b.z); v[7] = f2b(b.w);
        *reinterpret_cast<bf16x8*>(Xb + (size_t)i * 8) = v;
        return;
    }
    // transpose sections: src[R][C] -> dst[C][R]
    const float* src; short* dst; int R, C, bx, by;
    if (bid < kBlkX + kBlkWq) {
        const int local = bid - kBlkX;
        src = Wq; dst = WqT; R = kD; C = k3D; bx = local % 72; by = local / 72;
    } else {
        const int local = bid - kBlkX - kBlkWq;
        src = Wo; dst = WoT; R = kD; C = kD; bx = local % 24; by = local / 24;
    }
    __shared__ float t[32][33];
    const int c0 = bx * 32, r0 = by * 32;
    const int tx = tid & 31, ty = tid >> 5;
    #pragma unroll
    for (int i = ty; i < 32; i += 8)
        t[i][tx] = src[(size_t)(r0 + i) * C + c0 + tx];
    __syncthreads();
    #pragma unroll
    for (int i = ty; i < 32; i += 8)
        dst[(size_t)(c0 + i) * R + r0 + tx] = f2b(t[tx][i]);
}

// C[M x N] = A[M x K] * BT[N x K]^T, bf16 in, fp32 acc. 128x128 tile, BK=32.
// m97 structure: async global->LDS staging (16B), unpadded tiles, XOR swizzle.
// MODE 0: Cout fp32 = C + bias;  MODE 1: scatter bf16 Qh(*kQScale), Kh, Vt[h][d][n]
template<int MODE>
__device__ __forceinline__
void gemm_core(const short* __restrict__ A, const short* __restrict__ BT,
               const float* __restrict__ bias, float* __restrict__ Cout,
               short* __restrict__ Qh, short* __restrict__ Kh, short* __restrict__ Vt,
               int N, int K)
{
    const int bm   = blockIdx.x * 128;
    const int bn   = blockIdx.y * 128;
    const int tid  = threadIdx.x;
    const int wave = tid >> 6;
    const int lane = tid & 63;
    const int l15  = lane & 15;
    const int quad = lane >> 4;
    const int l3   = l15 & 3;

    __shared__ alignas(16) short As[128 * 32];
    __shared__ alignas(16) short Bs[128 * 32];

    floatx4 acc[4][4] = {};
    const int wm = (wave >> 1) * 64;
    const int wn = (wave & 1) * 64;

    // staging: 16 rows per issue (4 lanes/row), 2 issues/wave per buffer
    const int srl = lane >> 2;               // row within issue group (0..15)
    const int scc = (lane & 3) ^ (srl & 3);  // swizzled source chunk

    for (int k0 = 0; k0 < K; k0 += 32) {
        __syncthreads();
        #pragma unroll
        for (int j = 0; j < 2; ++j) {
            const int rs = 32 * wave + 16 * j;     // wave-uniform row start
            async_copy16(&A [(size_t)(bm + rs + srl) * K + k0 + 8 * scc], &As[rs * 32]);
            async_copy16(&BT[(size_t)(bn + rs + srl) * K + k0 + 8 * scc], &Bs[rs * 32]);
        }
        __syncthreads();

        bf16x8 af[4], bfr[4];
        #pragma unroll
        for (int mt = 0; mt < 4; ++mt)
            af[mt] = *reinterpret_cast<const bf16x8*>(&As[(wm + 16 * mt + l15) * 32 + 8 * (quad ^ l3)]);
        #pragma unroll
        for (int nt = 0; nt < 4; ++nt)
            bfr[nt] = *reinterpret_cast<const bf16x8*>(&Bs[(wn + 16 * nt + l15) * 32 + 8 * (quad ^ l3)]);
        #pragma unroll
        for (int mt = 0; mt < 4; ++mt)
            #pragma unroll
            for (int nt = 0; nt < 4; ++nt)
                acc[mt][nt] = __builtin_amdgcn_mfma_f32_16x16x32_bf16(af[mt], bfr[nt], acc[mt][nt], 0, 0, 0);
    }

    #pragma unroll
    for (int mt = 0; mt < 4; ++mt) {
        #pragma unroll
        for (int nt = 0; nt < 4; ++nt) {
            #pragma unroll
            for (int r = 0; r < 4; ++r) {
                const int row = bm + wm + mt * 16 + 4 * quad + r;
                const int col = bn + wn + nt * 16 + l15;
                float v = acc[mt][nt][r];
                if (MODE == 0) {
                    Cout[(size_t)row * N + col] = v + bias[col];
                } else {
                    const int proj   = col / kD;       // blocks never span projections
                    const int within = col - proj * kD;
                    const int h = within >> 6;
                    const int d = within & 63;
                    if (proj == 0)      Qh[((size_t)h * kN + row) * kHD + d] = f2b(v * kQScale);
                    else if (proj == 1) Kh[((size_t)h * kN + row) * kHD + d] = f2b(v);
                    else                Vt[((size_t)h * kHD + d) * kN + row] = f2b(v);
                }
            }
        }
    }
}

__global__ __launch_bounds__(256)
void gemm_qkv(const short* __restrict__ A, const short* __restrict__ BT,
              short* __restrict__ Qh, short* __restrict__ Kh, short* __restrict__ Vt)
{
    gemm_core<1>(A, BT, nullptr, nullptr, Qh, Kh, Vt, k3D, kD);
}

__global__ __launch_bounds__(256)
void gemm_out(const short* __restrict__ A, const short* __restrict__ BT,
              const float* __restrict__ bias, float* __restrict__ Cout)
{
    gemm_core<0>(A, BT, bias, Cout, nullptr, nullptr, nullptr, kD, kD);
}

// Flash attention v7: zero-LDS main loop, L2-direct K/V fragments.
// Evidence r5: with the pipeline in place, the LDS pipe is the top consumer
// (12 waves x 8 ds_read_b128 x ~10-12cyc ~= the whole 1082-cyc CU window),
// while per-XCD K/V working set (~1.5MB with the remap) is fully L2-resident.
// Staging L2-fit data through LDS is pure overhead (common-mistake #7).
// v7: kf/vv fragments load straight from global (L2-hit) into registers --
// no swizzle needed, the [h][n][d] / [h][d][n] layouts give the exact lane
// patterns. No staging, no dbuf LDS, and NO barriers in the main loop: waves
// free-run (the barrier-lockstep plateau disappears). Latency: kf reloads
// right after its last MFMA use, vv right after PV -- ~300+ cyc slack vs
// ~200 cyc L2 latency, compiler inserts per-register vmcnt waits.
// Kept from v5/v6: 2x2 wave split (2x read redundancy, ~24 TB/s L2 demand
// vs 34.5 ceiling), in-register P via cvt_pk+permlane, ones-MFMA denominator,
// bijective XCD remap. LDS: 16KB epilogue reduction only.
__global__ __launch_bounds__(256)
void attn(const short* __restrict__ Qh, const short* __restrict__ Kh,
          const short* __restrict__ Vt, short* __restrict__ AO)
{
    const int flat = blockIdx.y * 64 + blockIdx.x;    // 0..767
    const int W    = (flat & 7) * 96 + (flat >> 3);   // bijective XCD remap
    const int h    = W >> 6;                          // W / 64
    const int q0   = (W & 63) * 64;

    const int tid  = threadIdx.x;
    const int wave = tid >> 6;          // 0..3
    const int lane = tid & 63;
    const int l15  = lane & 15;
    const int quad = lane >> 4;
    const int wm   = wave >> 1;         // Q-row half owner
    const int wk   = wave & 1;          // KV half owner

    __shared__ alignas(16) float red[4096];     // 16KB epilogue O-reduction
    __shared__ float Dr[2][2][16];              // [wm][mt][4*quad+r] denom partials

    // Q fragments: B-operand of QK^T. qf[mt][s] = Q[q0+32wm+16mt+l15][32s+8quad..)
    bf16x8 qf[2][2];
    {
        const size_t qb = ((size_t)h * kN + q0 + 32 * wm + l15) * kHD;
        #pragma unroll
        for (int mt = 0; mt < 2; ++mt)
            #pragma unroll
            for (int s = 0; s < 2; ++s)
                qf[mt][s] = *reinterpret_cast<const bf16x8*>(
                    &Qh[qb + (size_t)(16 * mt) * kHD + 32 * s + 8 * quad]);
    }

    // all-ones B fragment: mfma(pa, ones) sums each P row -> softmax denom;
    // C-layout puts denom[row=16mt+4quad+r] in reg r of every lane.
    bf16x8 onesf;
    #pragma unroll
    for (int i = 0; i < 8; ++i) onesf[i] = (short)0x3F80;

    floatx4 oacc[2][4] = {};   // [mt][dt]: rows 32wm+16mt+4quad+r, cols 16dt+l15
    floatx4 dacc[2] = {};      // [mt] denom partial (this wave's kv half)

    // per-lane fragment base pointers (L2-resident; no swizzle needed)
    // kf(nt,s) at kv row (kv0 + 32wk + 16nt + l15), d cols 32s+8quad..+8
    const short* kp = Kh + (size_t)h * kN * kHD
                         + (size_t)(32 * wk + l15) * kHD + 8 * quad;
    // vv(dt) at d row (16dt + l15), kv cols kv0 + 32wk + 8quad..+8
    const short* vp = Vt + (size_t)h * kHD * kN
                         + (size_t)l15 * kN + 32 * wk + 8 * quad;

    auto load_k = [&](int kv0, bf16x8 (&kf)[2][2]) {
        #pragma unroll
        for (int nt = 0; nt < 2; ++nt)
            #pragma unroll
            for (int s = 0; s < 2; ++s)
                kf[nt][s] = *reinterpret_cast<const bf16x8*>(
                    kp + (size_t)(kv0 + 16 * nt) * kHD + 32 * s);
    };
    auto load_v = [&](int kv0, bf16x8 (&vv)[4]) {
        #pragma unroll
        for (int dt = 0; dt < 4; ++dt)
            vv[dt] = *reinterpret_cast<const bf16x8*>(
                vp + (size_t)(16 * dt) * kN + kv0);
    };

    // QK MFMAs only (sacc out); exp/pack split off so kf reload can issue
    // between the two (right after kf's last use).
    auto qk = [&](const bf16x8 (&kf)[2][2], floatx4 (&sacc)[2][2]) {
        __builtin_amdgcn_s_setprio(1);
        #pragma unroll
        for (int nt = 0; nt < 2; ++nt)
            #pragma unroll
            for (int s = 0; s < 2; ++s)
                #pragma unroll
                for (int mt = 0; mt < 2; ++mt)
                    sacc[mt][nt] = __builtin_amdgcn_mfma_f32_16x16x32_bf16(
                        kf[nt][s], qf[mt][s], sacc[mt][nt], 0, 0, 0);
        __builtin_amdgcn_s_setprio(0);
    };

    // producer lane(l15,q') holds P[m][kv=16nt+4q'+r]; A-frag word algebra:
    // w0=[X0 X2 Y0 Y2], w2=[X1 X3 Y1 Y3] over quads = swap16(swap32(X,Y)).
    auto expack = [&](const floatx4 (&sacc)[2][2], bf16x8 (&pa)[2]) {
        #pragma unroll
        for (int mt = 0; mt < 2; ++mt) {
            float e[2][4];
            #pragma unroll
            for (int nt = 0; nt < 2; ++nt)
                #pragma unroll
                for (int r = 0; r < 4; ++r)
                    e[nt][r] = fast_exp2(sacc[mt][nt][r]);
            unsigned x0 = cvt_pk_bf16(e[0][0], e[0][1]);
            unsigned y0 = cvt_pk_bf16(e[1][0], e[1][1]);
            unsigned x1 = cvt_pk_bf16(e[0][2], e[0][3]);
            unsigned y1 = cvt_pk_bf16(e[1][2], e[1][3]);
            permlane32_swap(x0, y0);
            permlane16_swap(x0, y0);
            permlane32_swap(x1, y1);
            permlane16_swap(x1, y1);
            union { uint4v u; bf16x8 v; } pu;
            pu.u[0] = x0; pu.u[1] = x1; pu.u[2] = y0; pu.u[3] = y1;
            pa[mt] = pu.v;
        }
    };

    auto pv = [&](const bf16x8 (&vv)[4], const bf16x8 (&pa)[2]) {
        __builtin_amdgcn_s_setprio(1);
        #pragma unroll
        for (int dt = 0; dt < 4; ++dt)
            #pragma unroll
            for (int mt = 0; mt < 2; ++mt)
                oacc[mt][dt] = __builtin_amdgcn_mfma_f32_16x16x32_bf16(
                    pa[mt], vv[dt], oacc[mt][dt], 0, 0, 0);
        #pragma unroll
        for (int mt = 0; mt < 2; ++mt)
            dacc[mt] = __builtin_amdgcn_mfma_f32_16x16x32_bf16(
                pa[mt], onesf, dacc[mt], 0, 0, 0);
        __builtin_amdgcn_s_setprio(0);
    };

    constexpr int kNT = kN / 64;   // 64 windows, no barriers
    bf16x8 kf[2][2], vv[4], pa[2];
    load_k(0, kf);
    load_v(0, vv);

    for (int u = 0; u < kNT; ++u) {
        floatx4 sacc[2][2] = {};
        qk(kf, sacc);                         // last use of kf(u)
        if (u + 1 < kNT) load_k((u + 1) * 64, kf);   // reload; ~expack+pv slack
        expack(sacc, pa);
        pv(vv, pa);                           // last use of vv(u)
        if (u + 1 < kNT) load_v((u + 1) * 64, vv);   // reload; ~qk+expack slack
    }

    // ---- epilogue: combine wk=0/1 partials (O and denom) ----
    if (wk == 1) {
        #pragma unroll
        for (int mt = 0; mt < 2; ++mt)
            #pragma unroll
            for (int dt = 0; dt < 4; ++dt)
                *reinterpret_cast<floatx4*>(
                    &red[wm * 2048 + (mt * 4 + dt) * 256 + l15 * 16 + quad * 4]) =
                    oacc[mt][dt];
        if (l15 == 0) {
            #pragma unroll
            for (int mt = 0; mt < 2; ++mt)
                #pragma unroll
                for (int r = 0; r < 4; ++r)
                    Dr[wm][mt][4 * quad + r] = dacc[mt][r];
        }
    }
    __syncthreads();
    if (wk == 0) {
        #pragma unroll
        for (int mt = 0; mt < 2; ++mt) {
            #pragma unroll
            for (int dt = 0; dt < 4; ++dt)
                oacc[mt][dt] += *reinterpret_cast<const floatx4*>(
                    &red[wm * 2048 + (mt * 4 + dt) * 256 + l15 * 16 + quad * 4]);
            float inv[4];
            #pragma unroll
            for (int r = 0; r < 4; ++r)
                inv[r] = 1.0f / (dacc[mt][r] + Dr[wm][mt][4 * quad + r]);
            #pragma unroll
            for (int dt = 0; dt < 4; ++dt) {
                #pragma unroll
                for (int r = 0; r < 4; ++r) {
                    const int row = q0 + 32 * wm + 16 * mt + 4 * quad + r;
                    const int col = h * kHD + 16 * dt + l15;
                    AO[(size_t)row * kD + col] = f2b(oacc[mt][dt][r] * inv[r]);
                }
            }
        }
    }
}

extern "C" void kernel_launch(void* const* d_in, const int* in_sizes, int n_in,
                              void* d_out, int out_size, void* d_ws, size_t ws_size,
                              hipStream_t stream)
{
    const float* x     = (const float*)d_in[0];  // (4096, 768) fp32
    const float* W_qkv = (const float*)d_in[1];  // (768, 2304) fp32
    const float* W_out = (const float*)d_in[2];  // (768, 768)  fp32
    const float* b_out = (const float*)d_in[3];  // (768,)      fp32
    float* out = (float*)d_out;                  // (4096, 768) fp32

    const size_t HNHD = (size_t)kH * kN * kHD;   // 3,145,728 shorts per tensor
    short* Qh    = (short*)d_ws;                 // [H][N][64]
    short* Kh    = Qh + HNHD;
    short* Vt    = Kh + HNHD;                    // [H][64][N]
    short* Xb    = Vt + HNHD;                    // x bf16 [N][768]; reused as AO
    short* WqkvT = Xb + (size_t)kN * kD;         // [2304][768]
    short* WoutT = WqkvT + (size_t)k3D * kD;     // [768][768]
    short* AO    = Xb;                           // overlay: Xb dead after QKV gemm
    (void)in_sizes; (void)n_in; (void)out_size; (void)ws_size;

    // 0) fused conversions/transposes (one launch)
    prep<<<dim3(kBlkX + kBlkWq + kBlkWo), dim3(256), 0, stream>>>(
        x, W_qkv, W_out, Xb, WqkvT, WoutT);

    // 1) QKV projection + head scatter (Q pre-scaled, V transposed)
    gemm_qkv<<<dim3(kN / 128, k3D / 128), dim3(256), 0, stream>>>(
        Xb, WqkvT, Qh, Kh, Vt);
    // 2) flash attention (zero-LDS main loop, L2-direct K/V)
    attn<<<dim3(kN / 64, kH), dim3(256), 0, stream>>>(Qh, Kh, Vt, AO);
    // 3) output projection + bias -> fp32
    gemm_out<<<dim3(kN / 128, kD / 128), dim3(256), 0, stream>>>(
        AO, WoutT, b_out, out);
}

// Round 8
// 202.305 us; speedup vs baseline: 1.4586x; 1.4586x over previous
//
#include <hip/hip_runtime.h>
#include <hip/hip_bf16.h>
#include <math.h>

typedef __attribute__((ext_vector_type(8))) short bf16x8;
typedef __attribute__((ext_vector_type(4))) short bf16x4;
typedef __attribute__((ext_vector_type(4))) float floatx4;
typedef __attribute__((ext_vector_type(4))) unsigned int uint4v;

constexpr int kN  = 4096;
constexpr int kD  = 768;
constexpr int kH  = 12;
constexpr int kHD = 64;
constexpr int k3D = 2304;
// Q pre-scale: (1/sqrt(64)) * log2(e) so softmax runs in exp2 domain with no muls
constexpr float kQScale = 0.18033688011112042f;

static __device__ __forceinline__ short f2b(float f) {
    __hip_bfloat16 h = __float2bfloat16(f);
    return *reinterpret_cast<short*>(&h);
}

static __device__ __forceinline__ float fast_exp2(float x) {
#if __has_builtin(__builtin_amdgcn_exp2f)
    return __builtin_amdgcn_exp2f(x);
#else
    return exp2f(x);
#endif
}

// v_cvt_pk_bf16_f32: pack two f32 -> one dword of 2 bf16 (lo, hi)
static __device__ __forceinline__ unsigned cvt_pk_bf16(float lo, float hi) {
    unsigned r;
    asm("v_cvt_pk_bf16_f32 %0, %1, %2" : "=v"(r) : "v"(lo), "v"(hi));
    return r;
}
// permlane swaps (gfx950): both operands read-modify-write.
static __device__ __forceinline__ void permlane32_swap(unsigned &a, unsigned &b) {
    asm("v_permlane32_swap_b32 %0, %1" : "+v"(a), "+v"(b));
}
static __device__ __forceinline__ void permlane16_swap(unsigned &a, unsigned &b) {
    asm("v_permlane16_swap_b32 %0, %1" : "+v"(a), "+v"(b));
}

// Async global->LDS DMA, 16B per lane. LDS dst is wave-uniform base + lane*16.
static __device__ __forceinline__ void async_copy16(const void* g, void* l) {
    __builtin_amdgcn_global_load_lds(
        (const __attribute__((address_space(1))) void*)g,
        (__attribute__((address_space(3))) void*)l, 16, 0, 0);
}

// Fused prep: section 0 = x fp32->bf16; section 1 = W_qkv transpose->bf16;
// section 2 = W_out transpose->bf16. One launch instead of three.
constexpr int kBlkX  = 1536;            // (4096*768/8)/256
constexpr int kBlkWq = 72 * 24;         // (2304/32) x (768/32)
constexpr int kBlkWo = 24 * 24;         // (768/32) x (768/32)

__global__ __launch_bounds__(256)
void prep(const float* __restrict__ x, const float* __restrict__ Wq,
          const float* __restrict__ Wo, short* __restrict__ Xb,
          short* __restrict__ WqT, short* __restrict__ WoT)
{
    const int bid = blockIdx.x;
    const int tid = threadIdx.x;
    if (bid < kBlkX) {
        const int i = bid * 256 + tid;
        const float4* s = reinterpret_cast<const float4*>(x + (size_t)i * 8);
        float4 a = s[0], b = s[1];
        bf16x8 v;
        v[0] = f2b(a.x); v[1] = f2b(a.y); v[2] = f2b(a.z); v[3] = f2b(a.w);
        v[4] = f2b(b.x); v[5] = f2b(b.y); v[6] = f2b(b.z); v[7] = f2b(b.w);
        *reinterpret_cast<bf16x8*>(Xb + (size_t)i * 8) = v;
        return;
    }
    // transpose sections: src[R][C] -> dst[C][R]
    const float* src; short* dst; int R, C, bx, by;
    if (bid < kBlkX + kBlkWq) {
        const int local = bid - kBlkX;
        src = Wq; dst = WqT; R = kD; C = k3D; bx = local % 72; by = local / 72;
    } else {
        const int local = bid - kBlkX - kBlkWq;
        src = Wo; dst = WoT; R = kD; C = kD; bx = local % 24; by = local / 24;
    }
    __shared__ float t[32][33];
    const int c0 = bx * 32, r0 = by * 32;
    const int tx = tid & 31, ty = tid >> 5;
    #pragma unroll
    for (int i = ty; i < 32; i += 8)
        t[i][tx] = src[(size_t)(r0 + i) * C + c0 + tx];
    __syncthreads();
    #pragma unroll
    for (int i = ty; i < 32; i += 8)
        dst[(size_t)(c0 + i) * R + r0 + tx] = f2b(t[tx][i]);
}

// C[M x N] = A[M x K] * BT[N x K]^T, bf16 in, fp32 acc. 128x128 tile, BK=32.
// m97 structure: async global->LDS staging (16B), unpadded tiles, XOR swizzle.
// MODE 0: Cout fp32 = C + bias;  MODE 1: scatter bf16 Qh(*kQScale), Kh, Vt[h][d][n]
// V-blocks (bn >= 1536) compute the TRANSPOSED tile via swapped-operand MFMA
// (A-frag and B-frag lane maps are identical; the XOR swizzle gives logical
// k-chunk = quad for both operands, so mfma(bfr, af) is layout-safe). The
// C-layout then puts token n on l15, so the Vt[h][d][n] store is 16-lane
// contiguous in n (32B runs, 4 segments/store) instead of a 64-lane 2B
// scatter at 8KB stride (64 segments/store).
template<int MODE>
__device__ __forceinline__
void gemm_core(const short* __restrict__ A, const short* __restrict__ BT,
               const float* __restrict__ bias, float* __restrict__ Cout,
               short* __restrict__ Qh, short* __restrict__ Kh, short* __restrict__ Vt,
               int N, int K)
{
    const int bm   = blockIdx.x * 128;
    const int bn   = blockIdx.y * 128;
    const int tid  = threadIdx.x;
    const int wave = tid >> 6;
    const int lane = tid & 63;
    const int l15  = lane & 15;
    const int quad = lane >> 4;
    const int l3   = l15 & 3;

    __shared__ alignas(16) short As[128 * 32];
    __shared__ alignas(16) short Bs[128 * 32];

    floatx4 acc[4][4] = {};
    const int wm = (wave >> 1) * 64;
    const int wn = (wave & 1) * 64;

    const bool vblk = (MODE == 1) && (bn >= 2 * kD);   // V projection block

    // staging: 16 rows per issue (4 lanes/row), 2 issues/wave per buffer
    const int srl = lane >> 2;               // row within issue group (0..15)
    const int scc = (lane & 3) ^ (srl & 3);  // swizzled source chunk

    for (int k0 = 0; k0 < K; k0 += 32) {
        __syncthreads();
        #pragma unroll
        for (int j = 0; j < 2; ++j) {
            const int rs = 32 * wave + 16 * j;     // wave-uniform row start
            async_copy16(&A [(size_t)(bm + rs + srl) * K + k0 + 8 * scc], &As[rs * 32]);
            async_copy16(&BT[(size_t)(bn + rs + srl) * K + k0 + 8 * scc], &Bs[rs * 32]);
        }
        __syncthreads();

        bf16x8 af[4], bfr[4];
        #pragma unroll
        for (int mt = 0; mt < 4; ++mt)
            af[mt] = *reinterpret_cast<const bf16x8*>(&As[(wm + 16 * mt + l15) * 32 + 8 * (quad ^ l3)]);
        #pragma unroll
        for (int nt = 0; nt < 4; ++nt)
            bfr[nt] = *reinterpret_cast<const bf16x8*>(&Bs[(wn + 16 * nt + l15) * 32 + 8 * (quad ^ l3)]);
        if (vblk) {
            // transposed tile: rows = projection cols, cols = tokens
            #pragma unroll
            for (int mt = 0; mt < 4; ++mt)
                #pragma unroll
                for (int nt = 0; nt < 4; ++nt)
                    acc[mt][nt] = __builtin_amdgcn_mfma_f32_16x16x32_bf16(bfr[nt], af[mt], acc[mt][nt], 0, 0, 0);
        } else {
            #pragma unroll
            for (int mt = 0; mt < 4; ++mt)
                #pragma unroll
                for (int nt = 0; nt < 4; ++nt)
                    acc[mt][nt] = __builtin_amdgcn_mfma_f32_16x16x32_bf16(af[mt], bfr[nt], acc[mt][nt], 0, 0, 0);
        }
    }

    if (vblk) {
        // acc[mt][nt][r] at lane(l15,quad): proj col c = bn+wn+16nt+4quad+r,
        // token n = bm+wm+16mt+l15. Store Vt[h][d][n], contiguous in n.
        #pragma unroll
        for (int mt = 0; mt < 4; ++mt) {
            #pragma unroll
            for (int nt = 0; nt < 4; ++nt) {
                #pragma unroll
                for (int r = 0; r < 4; ++r) {
                    const int c      = bn + wn + nt * 16 + 4 * quad + r;
                    const int n      = bm + wm + mt * 16 + l15;
                    const int within = c - 2 * kD;
                    const int h = within >> 6;
                    const int d = within & 63;
                    Vt[((size_t)h * kHD + d) * kN + n] = f2b(acc[mt][nt][r]);
                }
            }
        }
        return;
    }

    #pragma unroll
    for (int mt = 0; mt < 4; ++mt) {
        #pragma unroll
        for (int nt = 0; nt < 4; ++nt) {
            #pragma unroll
            for (int r = 0; r < 4; ++r) {
                const int row = bm + wm + mt * 16 + 4 * quad + r;
                const int col = bn + wn + nt * 16 + l15;
                float v = acc[mt][nt][r];
                if (MODE == 0) {
                    Cout[(size_t)row * N + col] = v + bias[col];
                } else {
                    const int proj   = col / kD;       // blocks never span projections
                    const int within = col - proj * kD;
                    const int h = within >> 6;
                    const int d = within & 63;
                    if (proj == 0)      Qh[((size_t)h * kN + row) * kHD + d] = f2b(v * kQScale);
                    else                Kh[((size_t)h * kN + row) * kHD + d] = f2b(v);
                }
            }
        }
    }
}

__global__ __launch_bounds__(256)
void gemm_qkv(const short* __restrict__ A, const short* __restrict__ BT,
              short* __restrict__ Qh, short* __restrict__ Kh, short* __restrict__ Vt)
{
    gemm_core<1>(A, BT, nullptr, nullptr, Qh, Kh, Vt, k3D, kD);
}

__global__ __launch_bounds__(256)
void gemm_out(const short* __restrict__ A, const short* __restrict__ BT,
              const float* __restrict__ bias, float* __restrict__ Cout)
{
    gemm_core<0>(A, BT, bias, Cout, nullptr, nullptr, nullptr, kD, kD);
}

// Flash attention v6 (verbatim revert -- best passing: attn 86.4us).
// Cross-tile software pipeline: each window has independent MFMA and VALU:
//   iter u: PV(u-1)            [MFMA: pa_prev + V(u-1) from old buffer]
//           barrier; stage(u+1) [into old buffer - PV reads already drained]
//           QK(u)              [MFMA from current buffer]
//           exp/pack(u)->pa     [VALU chain, overlaps next window's PV issue]
// v8 lesson: hoisting V to regs and moving PV after the stage overwrite
// failed correctness (unexplained race) -- do not resubmit without root cause.
__global__ __launch_bounds__(256)
void attn(const short* __restrict__ Qh, const short* __restrict__ Kh,
          const short* __restrict__ Vt, short* __restrict__ AO)
{
    const int flat = blockIdx.y * 64 + blockIdx.x;    // 0..767
    const int W    = (flat & 7) * 96 + (flat >> 3);   // bijective XCD remap
    const int h    = W >> 6;                          // W / 64
    const int q0   = (W & 63) * 64;

    const int tid  = threadIdx.x;
    const int wave = tid >> 6;          // 0..3
    const int lane = tid & 63;
    const int l15  = lane & 15;
    const int quad = lane >> 4;
    const int lx   = l15 & 7;
    const int wm   = wave >> 1;         // Q-row half owner
    const int wk   = wave & 1;          // KV half owner

    __shared__ alignas(16) short smem[16384];   // Ks[2]:0..8191, Vs[2]:8192..16383
    __shared__ float Dr[2][2][16];              // [wm][mt][4*quad+r] denom partials
    short* Ks0 = smem;
    short* Vs0 = smem + 8192;

    // Q fragments: B-operand of QK^T. qf[mt][s] = Q[q0+32wm+16mt+l15][32s+8quad..)
    bf16x8 qf[2][2];
    {
        const size_t qb = ((size_t)h * kN + q0 + 32 * wm + l15) * kHD;
        #pragma unroll
        for (int mt = 0; mt < 2; ++mt)
            #pragma unroll
            for (int s = 0; s < 2; ++s)
                qf[mt][s] = *reinterpret_cast<const bf16x8*>(
                    &Qh[qb + (size_t)(16 * mt) * kHD + 32 * s + 8 * quad]);
    }

    // all-ones B fragment: mfma(pa, ones) sums each P row -> softmax denom;
    // C-layout puts denom[row=16mt+4quad+r] in reg r of every lane.
    bf16x8 onesf;
    #pragma unroll
    for (int i = 0; i < 8; ++i) onesf[i] = (short)0x3F80;

    floatx4 oacc[2][4] = {};   // [mt][dt]: rows 32wm+16mt+4quad+r, cols 16dt+l15
    floatx4 dacc[2] = {};      // [mt] denom partial (this wave's kv half)

    // staging lane constants: each issue = 8 rows x 128B; physical chunk
    // (lane&7) holds logical chunk (lane&7)^(row&7)  (XOR swizzle)
    const int srl = lane >> 3;              // row within 8-row issue
    const int scc = (lane & 7) ^ srl;       // swizzled source chunk

    // hoisted per-lane staging base pointers (row 16*wave + srl, chunk scc)
    const short* kgp = &Kh[(size_t)h * kN * kHD +
                           (size_t)(16 * wave + srl) * kHD + 8 * scc];
    const short* vgp = &Vt[(size_t)h * kHD * kN +
                           (size_t)(16 * wave + srl) * kN + 8 * scc];
    short* kls = Ks0 + (16 * wave) * 64;    // wave's LDS dst base (K)
    short* vls = Vs0 + (16 * wave) * 64;    // wave's LDS dst base (V)

    auto stage = [&](int b, int kv0) {
        #pragma unroll
        for (int j = 0; j < 2; ++j) {
            async_copy16(kgp + (size_t)(kv0 + 8 * j) * kHD, kls + b * 4096 + (8 * j) * 64);
            async_copy16(vgp + (size_t)(8 * j) * kN + kv0,  vls + b * 4096 + (8 * j) * 64);
        }
    };

    // QK for tile in Kc, then exp/pack into pa (in-register A-fragment).
    auto qk_exp = [&](const short* Kc, bf16x8 (&pa)[2]) {
        floatx4 sacc[2][2] = {};   // [mt][nt]
        __builtin_amdgcn_s_setprio(1);
        #pragma unroll
        for (int nt = 0; nt < 2; ++nt) {
            #pragma unroll
            for (int s = 0; s < 2; ++s) {
                bf16x8 kf = *reinterpret_cast<const bf16x8*>(
                    &Kc[(32 * wk + 16 * nt + l15) * 64 + 8 * ((4 * s + quad) ^ lx)]);
                #pragma unroll
                for (int mt = 0; mt < 2; ++mt)
                    sacc[mt][nt] = __builtin_amdgcn_mfma_f32_16x16x32_bf16(
                        kf, qf[mt][s], sacc[mt][nt], 0, 0, 0);
            }
        }
        __builtin_amdgcn_s_setprio(0);
        // producer lane(l15,q') holds P[m][kv=16nt+4q'+r]; A-frag word algebra:
        // w0=[X0 X2 Y0 Y2], w2=[X1 X3 Y1 Y3] over quads = swap16(swap32(X,Y)).
        #pragma unroll
        for (int mt = 0; mt < 2; ++mt) {
            float e[2][4];
            #pragma unroll
            for (int nt = 0; nt < 2; ++nt)
                #pragma unroll
                for (int r = 0; r < 4; ++r)
                    e[nt][r] = fast_exp2(sacc[mt][nt][r]);
            unsigned x0 = cvt_pk_bf16(e[0][0], e[0][1]);
            unsigned y0 = cvt_pk_bf16(e[1][0], e[1][1]);
            unsigned x1 = cvt_pk_bf16(e[0][2], e[0][3]);
            unsigned y1 = cvt_pk_bf16(e[1][2], e[1][3]);
            permlane32_swap(x0, y0);
            permlane16_swap(x0, y0);
            permlane32_swap(x1, y1);
            permlane16_swap(x1, y1);
            union { uint4v u; bf16x8 v; } pu;
            pu.u[0] = x0; pu.u[1] = x1; pu.u[2] = y0; pu.u[3] = y1;
            pa[mt] = pu.v;
        }
    };

    // PV + denom for the tile whose V lives in Vc, P in pa.
    auto pv = [&](const short* Vc, const bf16x8 (&pa)[2]) {
        __builtin_amdgcn_s_setprio(1);
        #pragma unroll
        for (int dt = 0; dt < 4; ++dt) {
            bf16x8 vv = *reinterpret_cast<const bf16x8*>(
                &Vc[(16 * dt + l15) * 64 + 8 * ((4 * wk + quad) ^ lx)]);
            #pragma unroll
            for (int mt = 0; mt < 2; ++mt)
                oacc[mt][dt] = __builtin_amdgcn_mfma_f32_16x16x32_bf16(
                    pa[mt], vv, oacc[mt][dt], 0, 0, 0);
        }
        #pragma unroll
        for (int mt = 0; mt < 2; ++mt)
            dacc[mt] = __builtin_amdgcn_mfma_f32_16x16x32_bf16(
                pa[mt], onesf, dacc[mt], 0, 0, 0);
        __builtin_amdgcn_s_setprio(0);
    };

    constexpr int kNT = kN / 64;   // 64 tiles
    bf16x8 paA[2], paB[2];

    // tile 0 (no PV yet)
    stage(0, 0);
    __syncthreads();               // stage(0) drained
    stage(1, 64);
    qk_exp(Ks0, paA);
    int cur = 1;

    // tiles 1..62 in pairs (31 pairs); invariant at entry: buf[cur]=tile u,
    // buf[cur^1]=tile u-1, pa holds P(u-1).
    for (int tp = 0; tp < 31; ++tp) {
        const int u = 2 * tp + 1;
        // --- tile u ---
        pv(Vs0 + (cur ^ 1) * 4096, paA);
        __syncthreads();           // PV reads done everywhere; stage(u) drained
        stage(cur ^ 1, (u + 1) * 64);
        qk_exp(Ks0 + cur * 4096, paB);
        cur ^= 1;
        // --- tile u+1 ---
        pv(Vs0 + (cur ^ 1) * 4096, paB);
        __syncthreads();
        stage(cur ^ 1, (u + 2) * 64);
        qk_exp(Ks0 + cur * 4096, paA);
        cur ^= 1;
    }

    // tile 63
    pv(Vs0 + (cur ^ 1) * 4096, paA);
    __syncthreads();               // stage(63) drained
    qk_exp(Ks0 + cur * 4096, paB);
    pv(Vs0 + cur * 4096, paB);     // final PV (no further staging)

    // ---- epilogue: combine wk=0/1 partials (O and denom) ----
    __syncthreads();   // all main-loop LDS reads done; smem reusable
    float* red = reinterpret_cast<float*>(smem);   // 4096 floats = 16KB
    if (wk == 1) {
        #pragma unroll
        for (int mt = 0; mt < 2; ++mt)
            #pragma unroll
            for (int dt = 0; dt < 4; ++dt)
                *reinterpret_cast<floatx4*>(
                    &red[wm * 2048 + (mt * 4 + dt) * 256 + l15 * 16 + quad * 4]) =
                    oacc[mt][dt];
        if (l15 == 0) {
            #pragma unroll
            for (int mt = 0; mt < 2; ++mt)
                #pragma unroll
                for (int r = 0; r < 4; ++r)
                    Dr[wm][mt][4 * quad + r] = dacc[mt][r];
        }
    }
    __syncthreads();
    if (wk == 0) {
        #pragma unroll
        for (int mt = 0; mt < 2; ++mt) {
            #pragma unroll
            for (int dt = 0; dt < 4; ++dt)
                oacc[mt][dt] += *reinterpret_cast<const floatx4*>(
                    &red[wm * 2048 + (mt * 4 + dt) * 256 + l15 * 16 + quad * 4]);
            float inv[4];
            #pragma unroll
            for (int r = 0; r < 4; ++r)
                inv[r] = 1.0f / (dacc[mt][r] + Dr[wm][mt][4 * quad + r]);
            #pragma unroll
            for (int dt = 0; dt < 4; ++dt) {
                #pragma unroll
                for (int r = 0; r < 4; ++r) {
                    const int row = q0 + 32 * wm + 16 * mt + 4 * quad + r;
                    const int col = h * kHD + 16 * dt + l15;
                    AO[(size_t)row * kD + col] = f2b(oacc[mt][dt][r] * inv[r]);
                }
            }
        }
    }
}

extern "C" void kernel_launch(void* const* d_in, const int* in_sizes, int n_in,
                              void* d_out, int out_size, void* d_ws, size_t ws_size,
                              hipStream_t stream)
{
    const float* x     = (const float*)d_in[0];  // (4096, 768) fp32
    const float* W_qkv = (const float*)d_in[1];  // (768, 2304) fp32
    const float* W_out = (const float*)d_in[2];  // (768, 768)  fp32
    const float* b_out = (const float*)d_in[3];  // (768,)      fp32
    float* out = (float*)d_out;                  // (4096, 768) fp32

    const size_t HNHD = (size_t)kH * kN * kHD;   // 3,145,728 shorts per tensor
    short* Qh    = (short*)d_ws;                 // [H][N][64]
    short* Kh    = Qh + HNHD;
    short* Vt    = Kh + HNHD;                    // [H][64][N]
    short* Xb    = Vt + HNHD;                    // x bf16 [N][768]; reused as AO
    short* WqkvT = Xb + (size_t)kN * kD;         // [2304][768]
    short* WoutT = WqkvT + (size_t)k3D * kD;     // [768][768]
    short* AO    = Xb;                           // overlay: Xb dead after QKV gemm
    (void)in_sizes; (void)n_in; (void)out_size; (void)ws_size;

    // 0) fused conversions/transposes (one launch)
    prep<<<dim3(kBlkX + kBlkWq + kBlkWo), dim3(256), 0, stream>>>(
        x, W_qkv, W_out, Xb, WqkvT, WoutT);

    // 1) QKV projection + head scatter (Q pre-scaled, V transposed via
    //    swapped-operand MFMA -> coalesced Vt stores)
    gemm_qkv<<<dim3(kN / 128, k3D / 128), dim3(256), 0, stream>>>(
        Xb, WqkvT, Qh, Kh, Vt);
    // 2) flash attention (v6: 2x2 wave split, cross-tile software pipeline)
    attn<<<dim3(kN / 64, kH), dim3(256), 0, stream>>>(Qh, Kh, Vt, AO);
    // 3) output projection + bias -> fp32
    gemm_out<<<dim3(kN / 128, kD / 128), dim3(256), 0, stream>>>(
        AO, WoutT, b_out, out);
}

// Round 9
// 200.070 us; speedup vs baseline: 1.4749x; 1.0112x over previous
//
#include <hip/hip_runtime.h>
#include <hip/hip_bf16.h>
#include <math.h>

typedef __attribute__((ext_vector_type(8))) short bf16x8;
typedef __attribute__((ext_vector_type(4))) short bf16x4;
typedef __attribute__((ext_vector_type(4))) float floatx4;
typedef __attribute__((ext_vector_type(4))) unsigned int uint4v;

constexpr int kN  = 4096;
constexpr int kD  = 768;
constexpr int kH  = 12;
constexpr int kHD = 64;
constexpr int k3D = 2304;
// Q pre-scale: (1/sqrt(64)) * log2(e) so softmax runs in exp2 domain with no muls
constexpr float kQScale = 0.18033688011112042f;

static __device__ __forceinline__ short f2b(float f) {
    __hip_bfloat16 h = __float2bfloat16(f);
    return *reinterpret_cast<short*>(&h);
}

static __device__ __forceinline__ float fast_exp2(float x) {
#if __has_builtin(__builtin_amdgcn_exp2f)
    return __builtin_amdgcn_exp2f(x);
#else
    return exp2f(x);
#endif
}

// v_cvt_pk_bf16_f32: pack two f32 -> one dword of 2 bf16 (lo, hi)
static __device__ __forceinline__ unsigned cvt_pk_bf16(float lo, float hi) {
    unsigned r;
    asm("v_cvt_pk_bf16_f32 %0, %1, %2" : "=v"(r) : "v"(lo), "v"(hi));
    return r;
}
// permlane swaps (gfx950): both operands read-modify-write.
static __device__ __forceinline__ void permlane32_swap(unsigned &a, unsigned &b) {
    asm("v_permlane32_swap_b32 %0, %1" : "+v"(a), "+v"(b));
}
static __device__ __forceinline__ void permlane16_swap(unsigned &a, unsigned &b) {
    asm("v_permlane16_swap_b32 %0, %1" : "+v"(a), "+v"(b));
}

// Async global->LDS DMA, 16B per lane. LDS dst is wave-uniform base + lane*16.
static __device__ __forceinline__ void async_copy16(const void* g, void* l) {
    __builtin_amdgcn_global_load_lds(
        (const __attribute__((address_space(1))) void*)g,
        (__attribute__((address_space(3))) void*)l, 16, 0, 0);
}

// Fused prep: section 0 = x fp32->bf16; section 1 = W_qkv transpose->bf16;
// section 2 = W_out transpose->bf16. One launch instead of three.
constexpr int kBlkX  = 1536;            // (4096*768/8)/256
constexpr int kBlkWq = 72 * 24;         // (2304/32) x (768/32)
constexpr int kBlkWo = 24 * 24;         // (768/32) x (768/32)

__global__ __launch_bounds__(256)
void prep(const float* __restrict__ x, const float* __restrict__ Wq,
          const float* __restrict__ Wo, short* __restrict__ Xb,
          short* __restrict__ WqT, short* __restrict__ WoT)
{
    const int bid = blockIdx.x;
    const int tid = threadIdx.x;
    if (bid < kBlkX) {
        const int i = bid * 256 + tid;
        const float4* s = reinterpret_cast<const float4*>(x + (size_t)i * 8);
        float4 a = s[0], b = s[1];
        bf16x8 v;
        v[0] = f2b(a.x); v[1] = f2b(a.y); v[2] = f2b(a.z); v[3] = f2b(a.w);
        v[4] = f2b(b.x); v[5] = f2b(b.y); v[6] = f2b(b.z); v[7] = f2b(b.w);
        *reinterpret_cast<bf16x8*>(Xb + (size_t)i * 8) = v;
        return;
    }
    // transpose sections: src[R][C] -> dst[C][R]
    const float* src; short* dst; int R, C, bx, by;
    if (bid < kBlkX + kBlkWq) {
        const int local = bid - kBlkX;
        src = Wq; dst = WqT; R = kD; C = k3D; bx = local % 72; by = local / 72;
    } else {
        const int local = bid - kBlkX - kBlkWq;
        src = Wo; dst = WoT; R = kD; C = kD; bx = local % 24; by = local / 24;
    }
    __shared__ float t[32][33];
    const int c0 = bx * 32, r0 = by * 32;
    const int tx = tid & 31, ty = tid >> 5;
    #pragma unroll
    for (int i = ty; i < 32; i += 8)
        t[i][tx] = src[(size_t)(r0 + i) * C + c0 + tx];
    __syncthreads();
    #pragma unroll
    for (int i = ty; i < 32; i += 8)
        dst[(size_t)(c0 + i) * R + r0 + tx] = f2b(t[tx][i]);
}

// QKV projection: C[4096 x 2304] = Xb[4096 x 768] * WqT[2304 x 768]^T.
// 128x96 tile -> grid (32, 24) = 768 blocks = exactly 3 blocks/CU (the old
// 128x128 grid was 576 = 2.25/CU: the 0.25 tail idled 3/4 of the chip for
// a full block round, ~25% of the kernel). 96 | 768 and 96 | 1536 so blocks
// never span projections. V-blocks (bn >= 1536) compute the TRANSPOSED tile
// via swapped-operand MFMA (A/B fragment lane maps are identical; XOR
// swizzle gives logical k-chunk = quad for both operands) so the Vt[h][d][n]
// store is contiguous in n.
__global__ __launch_bounds__(256)
void gemm_qkv(const short* __restrict__ A, const short* __restrict__ BT,
              short* __restrict__ Qh, short* __restrict__ Kh, short* __restrict__ Vt)
{
    const int bm   = blockIdx.x * 128;
    const int bn   = blockIdx.y * 96;
    const int tid  = threadIdx.x;
    const int wave = tid >> 6;
    const int lane = tid & 63;
    const int l15  = lane & 15;
    const int quad = lane >> 4;
    const int l3   = l15 & 3;
    constexpr int K = kD;

    __shared__ alignas(16) short As[128 * 32];
    __shared__ alignas(16) short Bs[96 * 32];

    floatx4 acc[4][3] = {};
    const int wm = (wave >> 1) * 64;
    const int wn = (wave & 1) * 48;

    const bool vblk = (bn >= 2 * kD);        // V projection block

    // staging: 16 rows per issue (4 lanes/row, 64B rows)
    const int srl = lane >> 2;               // row within issue group (0..15)
    const int scc = (lane & 3) ^ (srl & 3);  // swizzled source chunk

    for (int k0 = 0; k0 < K; k0 += 32) {
        __syncthreads();
        #pragma unroll
        for (int j = 0; j < 2; ++j) {
            const int rs = 32 * wave + 16 * j;     // A rows: 8 issues over 4 waves
            async_copy16(&A[(size_t)(bm + rs + srl) * K + k0 + 8 * scc], &As[rs * 32]);
        }
        // B rows: 6 issues {0,16,32,48,64,80} over 4 waves (w0:0,64 w1:16,80
        // w2:32 w3:48)
        for (int rb = 16 * wave; rb < 96; rb += 64)
            async_copy16(&BT[(size_t)(bn + rb + srl) * K + k0 + 8 * scc], &Bs[rb * 32]);
        __syncthreads();

        bf16x8 af[4], bfr[3];
        #pragma unroll
        for (int mt = 0; mt < 4; ++mt)
            af[mt] = *reinterpret_cast<const bf16x8*>(&As[(wm + 16 * mt + l15) * 32 + 8 * (quad ^ l3)]);
        #pragma unroll
        for (int nt = 0; nt < 3; ++nt)
            bfr[nt] = *reinterpret_cast<const bf16x8*>(&Bs[(wn + 16 * nt + l15) * 32 + 8 * (quad ^ l3)]);
        if (vblk) {
            #pragma unroll
            for (int mt = 0; mt < 4; ++mt)
                #pragma unroll
                for (int nt = 0; nt < 3; ++nt)
                    acc[mt][nt] = __builtin_amdgcn_mfma_f32_16x16x32_bf16(bfr[nt], af[mt], acc[mt][nt], 0, 0, 0);
        } else {
            #pragma unroll
            for (int mt = 0; mt < 4; ++mt)
                #pragma unroll
                for (int nt = 0; nt < 3; ++nt)
                    acc[mt][nt] = __builtin_amdgcn_mfma_f32_16x16x32_bf16(af[mt], bfr[nt], acc[mt][nt], 0, 0, 0);
        }
    }

    if (vblk) {
        // transposed tile: proj col c = bn+wn+16nt+4quad+r, token n on l15.
        #pragma unroll
        for (int mt = 0; mt < 4; ++mt) {
            #pragma unroll
            for (int nt = 0; nt < 3; ++nt) {
                #pragma unroll
                for (int r = 0; r < 4; ++r) {
                    const int c      = bn + wn + nt * 16 + 4 * quad + r;
                    const int n      = bm + wm + mt * 16 + l15;
                    const int within = c - 2 * kD;
                    const int h = within >> 6;
                    const int d = within & 63;
                    Vt[((size_t)h * kHD + d) * kN + n] = f2b(acc[mt][nt][r]);
                }
            }
        }
        return;
    }

    #pragma unroll
    for (int mt = 0; mt < 4; ++mt) {
        #pragma unroll
        for (int nt = 0; nt < 3; ++nt) {
            #pragma unroll
            for (int r = 0; r < 4; ++r) {
                const int row = bm + wm + mt * 16 + 4 * quad + r;
                const int col = bn + wn + nt * 16 + l15;
                const float v = acc[mt][nt][r];
                const int proj   = col / kD;       // blocks never span projections
                const int within = col - proj * kD;
                const int h = within >> 6;
                const int d = within & 63;
                if (proj == 0) Qh[((size_t)h * kN + row) * kHD + d] = f2b(v * kQScale);
                else           Kh[((size_t)h * kN + row) * kHD + d] = f2b(v);
            }
        }
    }
}

// Output projection: out[4096 x 768] = AO * WoutT^T + bias.
// 64x64 tile -> grid (64, 12) = 768 blocks = exactly 3 blocks/CU. The old
// 128x128 grid was 192 blocks = 0.75/CU: a quarter of the chip idle and no
// cross-block latency hiding anywhere.
__global__ __launch_bounds__(256)
void gemm_out(const short* __restrict__ A, const short* __restrict__ BT,
              const float* __restrict__ bias, float* __restrict__ Cout)
{
    const int bm   = blockIdx.x * 64;
    const int bn   = blockIdx.y * 64;
    const int tid  = threadIdx.x;
    const int wave = tid >> 6;
    const int lane = tid & 63;
    const int l15  = lane & 15;
    const int quad = lane >> 4;
    const int l3   = l15 & 3;
    constexpr int K = kD;
    constexpr int N = kD;

    __shared__ alignas(16) short As[64 * 32];
    __shared__ alignas(16) short Bs[64 * 32];

    floatx4 acc[2][2] = {};
    const int wm = (wave >> 1) * 32;
    const int wn = (wave & 1) * 32;

    const int srl = lane >> 2;               // 16 rows/issue, 4 lanes/row
    const int scc = (lane & 3) ^ (srl & 3);  // swizzled source chunk

    for (int k0 = 0; k0 < K; k0 += 32) {
        __syncthreads();
        const int rs = 16 * wave;            // 4 issues cover 64 rows (A and B)
        async_copy16(&A [(size_t)(bm + rs + srl) * K + k0 + 8 * scc], &As[rs * 32]);
        async_copy16(&BT[(size_t)(bn + rs + srl) * K + k0 + 8 * scc], &Bs[rs * 32]);
        __syncthreads();

        bf16x8 af[2], bfr[2];
        #pragma unroll
        for (int mt = 0; mt < 2; ++mt)
            af[mt] = *reinterpret_cast<const bf16x8*>(&As[(wm + 16 * mt + l15) * 32 + 8 * (quad ^ l3)]);
        #pragma unroll
        for (int nt = 0; nt < 2; ++nt)
            bfr[nt] = *reinterpret_cast<const bf16x8*>(&Bs[(wn + 16 * nt + l15) * 32 + 8 * (quad ^ l3)]);
        #pragma unroll
        for (int mt = 0; mt < 2; ++mt)
            #pragma unroll
            for (int nt = 0; nt < 2; ++nt)
                acc[mt][nt] = __builtin_amdgcn_mfma_f32_16x16x32_bf16(af[mt], bfr[nt], acc[mt][nt], 0, 0, 0);
    }

    #pragma unroll
    for (int mt = 0; mt < 2; ++mt)
        #pragma unroll
        for (int nt = 0; nt < 2; ++nt)
            #pragma unroll
            for (int r = 0; r < 4; ++r) {
                const int row = bm + wm + mt * 16 + 4 * quad + r;
                const int col = bn + wn + nt * 16 + l15;
                Cout[(size_t)row * N + col] = acc[mt][nt][r] + bias[col];
            }
}

// Flash attention v6 (unchanged -- best passing: attn ~86-89us).
// Cross-tile software pipeline: each window has independent MFMA and VALU:
//   iter u: PV(u-1)            [MFMA: pa_prev + V(u-1) from old buffer]
//           barrier; stage(u+1) [into old buffer - PV reads already drained]
//           QK(u)              [MFMA from current buffer]
//           exp/pack(u)->pa     [VALU chain, overlaps next window's PV issue]
// v8 lesson: hoisting V to regs and moving PV after the stage overwrite
// failed correctness (unexplained race) -- do not resubmit without root cause.
__global__ __launch_bounds__(256)
void attn(const short* __restrict__ Qh, const short* __restrict__ Kh,
          const short* __restrict__ Vt, short* __restrict__ AO)
{
    const int flat = blockIdx.y * 64 + blockIdx.x;    // 0..767
    const int W    = (flat & 7) * 96 + (flat >> 3);   // bijective XCD remap
    const int h    = W >> 6;                          // W / 64
    const int q0   = (W & 63) * 64;

    const int tid  = threadIdx.x;
    const int wave = tid >> 6;          // 0..3
    const int lane = tid & 63;
    const int l15  = lane & 15;
    const int quad = lane >> 4;
    const int lx   = l15 & 7;
    const int wm   = wave >> 1;         // Q-row half owner
    const int wk   = wave & 1;          // KV half owner

    __shared__ alignas(16) short smem[16384];   // Ks[2]:0..8191, Vs[2]:8192..16383
    __shared__ float Dr[2][2][16];              // [wm][mt][4*quad+r] denom partials
    short* Ks0 = smem;
    short* Vs0 = smem + 8192;

    // Q fragments: B-operand of QK^T. qf[mt][s] = Q[q0+32wm+16mt+l15][32s+8quad..)
    bf16x8 qf[2][2];
    {
        const size_t qb = ((size_t)h * kN + q0 + 32 * wm + l15) * kHD;
        #pragma unroll
        for (int mt = 0; mt < 2; ++mt)
            #pragma unroll
            for (int s = 0; s < 2; ++s)
                qf[mt][s] = *reinterpret_cast<const bf16x8*>(
                    &Qh[qb + (size_t)(16 * mt) * kHD + 32 * s + 8 * quad]);
    }

    // all-ones B fragment: mfma(pa, ones) sums each P row -> softmax denom;
    // C-layout puts denom[row=16mt+4quad+r] in reg r of every lane.
    bf16x8 onesf;
    #pragma unroll
    for (int i = 0; i < 8; ++i) onesf[i] = (short)0x3F80;

    floatx4 oacc[2][4] = {};   // [mt][dt]: rows 32wm+16mt+4quad+r, cols 16dt+l15
    floatx4 dacc[2] = {};      // [mt] denom partial (this wave's kv half)

    // staging lane constants: each issue = 8 rows x 128B; physical chunk
    // (lane&7) holds logical chunk (lane&7)^(row&7)  (XOR swizzle)
    const int srl = lane >> 3;              // row within 8-row issue
    const int scc = (lane & 7) ^ srl;       // swizzled source chunk

    // hoisted per-lane staging base pointers (row 16*wave + srl, chunk scc)
    const short* kgp = &Kh[(size_t)h * kN * kHD +
                           (size_t)(16 * wave + srl) * kHD + 8 * scc];
    const short* vgp = &Vt[(size_t)h * kHD * kN +
                           (size_t)(16 * wave + srl) * kN + 8 * scc];
    short* kls = Ks0 + (16 * wave) * 64;    // wave's LDS dst base (K)
    short* vls = Vs0 + (16 * wave) * 64;    // wave's LDS dst base (V)

    auto stage = [&](int b, int kv0) {
        #pragma unroll
        for (int j = 0; j < 2; ++j) {
            async_copy16(kgp + (size_t)(kv0 + 8 * j) * kHD, kls + b * 4096 + (8 * j) * 64);
            async_copy16(vgp + (size_t)(8 * j) * kN + kv0,  vls + b * 4096 + (8 * j) * 64);
        }
    };

    // QK for tile in Kc, then exp/pack into pa (in-register A-fragment).
    auto qk_exp = [&](const short* Kc, bf16x8 (&pa)[2]) {
        floatx4 sacc[2][2] = {};   // [mt][nt]
        __builtin_amdgcn_s_setprio(1);
        #pragma unroll
        for (int nt = 0; nt < 2; ++nt) {
            #pragma unroll
            for (int s = 0; s < 2; ++s) {
                bf16x8 kf = *reinterpret_cast<const bf16x8*>(
                    &Kc[(32 * wk + 16 * nt + l15) * 64 + 8 * ((4 * s + quad) ^ lx)]);
                #pragma unroll
                for (int mt = 0; mt < 2; ++mt)
                    sacc[mt][nt] = __builtin_amdgcn_mfma_f32_16x16x32_bf16(
                        kf, qf[mt][s], sacc[mt][nt], 0, 0, 0);
            }
        }
        __builtin_amdgcn_s_setprio(0);
        // producer lane(l15,q') holds P[m][kv=16nt+4q'+r]; A-frag word algebra:
        // w0=[X0 X2 Y0 Y2], w2=[X1 X3 Y1 Y3] over quads = swap16(swap32(X,Y)).
        #pragma unroll
        for (int mt = 0; mt < 2; ++mt) {
            float e[2][4];
            #pragma unroll
            for (int nt = 0; nt < 2; ++nt)
                #pragma unroll
                for (int r = 0; r < 4; ++r)
                    e[nt][r] = fast_exp2(sacc[mt][nt][r]);
            unsigned x0 = cvt_pk_bf16(e[0][0], e[0][1]);
            unsigned y0 = cvt_pk_bf16(e[1][0], e[1][1]);
            unsigned x1 = cvt_pk_bf16(e[0][2], e[0][3]);
            unsigned y1 = cvt_pk_bf16(e[1][2], e[1][3]);
            permlane32_swap(x0, y0);
            permlane16_swap(x0, y0);
            permlane32_swap(x1, y1);
            permlane16_swap(x1, y1);
            union { uint4v u; bf16x8 v; } pu;
            pu.u[0] = x0; pu.u[1] = x1; pu.u[2] = y0; pu.u[3] = y1;
            pa[mt] = pu.v;
        }
    };

    // PV + denom for the tile whose V lives in Vc, P in pa.
    auto pv = [&](const short* Vc, const bf16x8 (&pa)[2]) {
        __builtin_amdgcn_s_setprio(1);
        #pragma unroll
        for (int dt = 0; dt < 4; ++dt) {
            bf16x8 vv = *reinterpret_cast<const bf16x8*>(
                &Vc[(16 * dt + l15) * 64 + 8 * ((4 * wk + quad) ^ lx)]);
            #pragma unroll
            for (int mt = 0; mt < 2; ++mt)
                oacc[mt][dt] = __builtin_amdgcn_mfma_f32_16x16x32_bf16(
                    pa[mt], vv, oacc[mt][dt], 0, 0, 0);
        }
        #pragma unroll
        for (int mt = 0; mt < 2; ++mt)
            dacc[mt] = __builtin_amdgcn_mfma_f32_16x16x32_bf16(
                pa[mt], onesf, dacc[mt], 0, 0, 0);
        __builtin_amdgcn_s_setprio(0);
    };

    constexpr int kNT = kN / 64;   // 64 tiles
    bf16x8 paA[2], paB[2];

    // tile 0 (no PV yet)
    stage(0, 0);
    __syncthreads();               // stage(0) drained
    stage(1, 64);
    qk_exp(Ks0, paA);
    int cur = 1;

    // tiles 1..62 in pairs (31 pairs); invariant at entry: buf[cur]=tile u,
    // buf[cur^1]=tile u-1, pa holds P(u-1).
    for (int tp = 0; tp < 31; ++tp) {
        const int u = 2 * tp + 1;
        // --- tile u ---
        pv(Vs0 + (cur ^ 1) * 4096, paA);
        __syncthreads();           // PV reads done everywhere; stage(u) drained
        stage(cur ^ 1, (u + 1) * 64);
        qk_exp(Ks0 + cur * 4096, paB);
        cur ^= 1;
        // --- tile u+1 ---
        pv(Vs0 + (cur ^ 1) * 4096, paB);
        __syncthreads();
        stage(cur ^ 1, (u + 2) * 64);
        qk_exp(Ks0 + cur * 4096, paA);
        cur ^= 1;
    }

    // tile 63
    pv(Vs0 + (cur ^ 1) * 4096, paA);
    __syncthreads();               // stage(63) drained
    qk_exp(Ks0 + cur * 4096, paB);
    pv(Vs0 + cur * 4096, paB);     // final PV (no further staging)

    // ---- epilogue: combine wk=0/1 partials (O and denom) ----
    __syncthreads();   // all main-loop LDS reads done; smem reusable
    float* red = reinterpret_cast<float*>(smem);   // 4096 floats = 16KB
    if (wk == 1) {
        #pragma unroll
        for (int mt = 0; mt < 2; ++mt)
            #pragma unroll
            for (int dt = 0; dt < 4; ++dt)
                *reinterpret_cast<floatx4*>(
                    &red[wm * 2048 + (mt * 4 + dt) * 256 + l15 * 16 + quad * 4]) =
                    oacc[mt][dt];
        if (l15 == 0) {
            #pragma unroll
            for (int mt = 0; mt < 2; ++mt)
                #pragma unroll
                for (int r = 0; r < 4; ++r)
                    Dr[wm][mt][4 * quad + r] = dacc[mt][r];
        }
    }
    __syncthreads();
    if (wk == 0) {
        #pragma unroll
        for (int mt = 0; mt < 2; ++mt) {
            #pragma unroll
            for (int dt = 0; dt < 4; ++dt)
                oacc[mt][dt] += *reinterpret_cast<const floatx4*>(
                    &red[wm * 2048 + (mt * 4 + dt) * 256 + l15 * 16 + quad * 4]);
            float inv[4];
            #pragma unroll
            for (int r = 0; r < 4; ++r)
                inv[r] = 1.0f / (dacc[mt][r] + Dr[wm][mt][4 * quad + r]);
            #pragma unroll
            for (int dt = 0; dt < 4; ++dt) {
                #pragma unroll
                for (int r = 0; r < 4; ++r) {
                    const int row = q0 + 32 * wm + 16 * mt + 4 * quad + r;
                    const int col = h * kHD + 16 * dt + l15;
                    AO[(size_t)row * kD + col] = f2b(oacc[mt][dt][r] * inv[r]);
                }
            }
        }
    }
}

extern "C" void kernel_launch(void* const* d_in, const int* in_sizes, int n_in,
                              void* d_out, int out_size, void* d_ws, size_t ws_size,
                              hipStream_t stream)
{
    const float* x     = (const float*)d_in[0];  // (4096, 768) fp32
    const float* W_qkv = (const float*)d_in[1];  // (768, 2304) fp32
    const float* W_out = (const float*)d_in[2];  // (768, 768)  fp32
    const float* b_out = (const float*)d_in[3];  // (768,)      fp32
    float* out = (float*)d_out;                  // (4096, 768) fp32

    const size_t HNHD = (size_t)kH * kN * kHD;   // 3,145,728 shorts per tensor
    short* Qh    = (short*)d_ws;                 // [H][N][64]
    short* Kh    = Qh + HNHD;
    short* Vt    = Kh + HNHD;                    // [H][64][N]
    short* Xb    = Vt + HNHD;                    // x bf16 [N][768]; reused as AO
    short* WqkvT = Xb + (size_t)kN * kD;         // [2304][768]
    short* WoutT = WqkvT + (size_t)k3D * kD;     // [768][768]
    short* AO    = Xb;                           // overlay: Xb dead after QKV gemm
    (void)in_sizes; (void)n_in; (void)out_size; (void)ws_size;

    // 0) fused conversions/transposes (one launch)
    prep<<<dim3(kBlkX + kBlkWq + kBlkWo), dim3(256), 0, stream>>>(
        x, W_qkv, W_out, Xb, WqkvT, WoutT);

    // 1) QKV projection + head scatter (128x96 tiles: 768 blocks = 3/CU)
    gemm_qkv<<<dim3(kN / 128, k3D / 96), dim3(256), 0, stream>>>(
        Xb, WqkvT, Qh, Kh, Vt);
    // 2) flash attention (v6: 2x2 wave split, cross-tile software pipeline)
    attn<<<dim3(kN / 64, kH), dim3(256), 0, stream>>>(Qh, Kh, Vt, AO);
    // 3) output projection + bias (64x64 tiles: 768 blocks = 3/CU)
    gemm_out<<<dim3(kN / 64, kD / 64), dim3(256), 0, stream>>>(
        AO, WoutT, b_out, out);
}

// Round 11
// 188.650 us; speedup vs baseline: 1.5641x; 1.0605x over previous
//
#include <hip/hip_runtime.h>
#include <hip/hip_bf16.h>
#include <math.h>

typedef __attribute__((ext_vector_type(8))) short bf16x8;
typedef __attribute__((ext_vector_type(4))) short bf16x4;
typedef __attribute__((ext_vector_type(4))) float floatx4;
typedef __attribute__((ext_vector_type(4))) unsigned int uint4v;

constexpr int kN  = 4096;
constexpr int kD  = 768;
constexpr int kH  = 12;
constexpr int kHD = 64;
constexpr int k3D = 2304;
// Q pre-scale: (1/sqrt(64)) * log2(e) so softmax runs in exp2 domain with no muls
constexpr float kQScale = 0.18033688011112042f;

static __device__ __forceinline__ short f2b(float f) {
    __hip_bfloat16 h = __float2bfloat16(f);
    return *reinterpret_cast<short*>(&h);
}

static __device__ __forceinline__ float fast_exp2(float x) {
#if __has_builtin(__builtin_amdgcn_exp2f)
    return __builtin_amdgcn_exp2f(x);
#else
    return exp2f(x);
#endif
}

// v_cvt_pk_bf16_f32: pack two f32 -> one dword of 2 bf16 (lo, hi)
static __device__ __forceinline__ unsigned cvt_pk_bf16(float lo, float hi) {
    unsigned r;
    asm("v_cvt_pk_bf16_f32 %0, %1, %2" : "=v"(r) : "v"(lo), "v"(hi));
    return r;
}
// permlane swaps (gfx950): both operands read-modify-write.
static __device__ __forceinline__ void permlane32_swap(unsigned &a, unsigned &b) {
    asm("v_permlane32_swap_b32 %0, %1" : "+v"(a), "+v"(b));
}
static __device__ __forceinline__ void permlane16_swap(unsigned &a, unsigned &b) {
    asm("v_permlane16_swap_b32 %0, %1" : "+v"(a), "+v"(b));
}

// Async global->LDS DMA, 16B per lane. LDS dst is wave-uniform base + lane*16.
static __device__ __forceinline__ void async_copy16(const void* g, void* l) {
    __builtin_amdgcn_global_load_lds(
        (const __attribute__((address_space(1))) void*)g,
        (__attribute__((address_space(3))) void*)l, 16, 0, 0);
}

// Fused prep: section 0 = x fp32->bf16; section 1 = W_qkv transpose->bf16;
// section 2 = W_out transpose->bf16. One launch instead of three.
constexpr int kBlkX  = 1536;            // (4096*768/8)/256
constexpr int kBlkWq = 72 * 24;         // (2304/32) x (768/32)
constexpr int kBlkWo = 24 * 24;         // (768/32) x (768/32)

__global__ __launch_bounds__(256)
void prep(const float* __restrict__ x, const float* __restrict__ Wq,
          const float* __restrict__ Wo, short* __restrict__ Xb,
          short* __restrict__ WqT, short* __restrict__ WoT)
{
    const int bid = blockIdx.x;
    const int tid = threadIdx.x;
    if (bid < kBlkX) {
        const int i = bid * 256 + tid;
        const float4* s = reinterpret_cast<const float4*>(x + (size_t)i * 8);
        float4 a = s[0], b = s[1];
        bf16x8 v;
        v[0] = f2b(a.x); v[1] = f2b(a.y); v[2] = f2b(a.z); v[3] = f2b(a.w);
        v[4] = f2b(b.x); v[5] = f2b(b.y); v[6] = f2b(b.z); v[7] = f2b(b.w);
        *reinterpret_cast<bf16x8*>(Xb + (size_t)i * 8) = v;
        return;
    }
    // transpose sections: src[R][C] -> dst[C][R]
    const float* src; short* dst; int R, C, bx, by;
    if (bid < kBlkX + kBlkWq) {
        const int local = bid - kBlkX;
        src = Wq; dst = WqT; R = kD; C = k3D; bx = local % 72; by = local / 72;
    } else {
        const int local = bid - kBlkX - kBlkWq;
        src = Wo; dst = WoT; R = kD; C = kD; bx = local % 24; by = local / 24;
    }
    __shared__ float t[32][33];
    const int c0 = bx * 32, r0 = by * 32;
    const int tx = tid & 31, ty = tid >> 5;
    #pragma unroll
    for (int i = ty; i < 32; i += 8)
        t[i][tx] = src[(size_t)(r0 + i) * C + c0 + tx];
    __syncthreads();
    #pragma unroll
    for (int i = ty; i < 32; i += 8)
        dst[(size_t)(c0 + i) * R + r0 + tx] = f2b(t[tx][i]);
}

// QKV projection: C[4096 x 2304] = Xb[4096 x 768] * WqT[2304 x 768]^T.
// 128x96 tile, grid (32,24) = 768 blocks = 3/CU. BK=64: 12 barrier windows
// of 24 MFMAs each (was 24 windows x 12 -- the per-window barrier drain was
// amortized over too little work). Staging rows are 128B (8 chunks of 16B),
// XOR swizzle chunk = logical ^ (row&7); all row bases are 0 mod 8 so the
// fragment-read swizzle is unchanged. V-blocks (bn >= 1536) compute the
// TRANSPOSED tile via swapped-operand MFMA so Vt[h][d][n] stores are
// contiguous in n.
__global__ __launch_bounds__(256)
void gemm_qkv(const short* __restrict__ A, const short* __restrict__ BT,
              short* __restrict__ Qh, short* __restrict__ Kh, short* __restrict__ Vt)
{
    const int bm   = blockIdx.x * 128;
    const int bn   = blockIdx.y * 96;
    const int tid  = threadIdx.x;
    const int wave = tid >> 6;
    const int lane = tid & 63;
    const int l15  = lane & 15;
    const int quad = lane >> 4;
    const int lx   = l15 & 7;
    constexpr int K = kD;

    __shared__ alignas(16) short As[128 * 64];   // 16KB
    __shared__ alignas(16) short Bs[96 * 64];    // 12KB

    floatx4 acc[4][3] = {};
    const int wm = (wave >> 1) * 64;
    const int wn = (wave & 1) * 48;

    const bool vblk = (bn >= 2 * kD);        // V projection block

    // staging: 8 rows (128B each) per issue; physical chunk (lane&7) holds
    // logical chunk (lane&7)^(row&7)
    const int srl = lane >> 3;               // row within 8-row issue (0..7)
    const int scc = (lane & 7) ^ srl;        // swizzled source chunk

    for (int k0 = 0; k0 < K; k0 += 64) {
        __syncthreads();
        #pragma unroll
        for (int j = 0; j < 4; ++j) {
            const int rs = 32 * wave + 8 * j;          // A rows: 16 issues / 4 waves
            async_copy16(&A[(size_t)(bm + rs + srl) * K + k0 + 8 * scc], &As[rs * 64]);
        }
        #pragma unroll
        for (int j = 0; j < 3; ++j) {
            const int rb = 24 * wave + 8 * j;          // B rows: 12 issues / 4 waves
            async_copy16(&BT[(size_t)(bn + rb + srl) * K + k0 + 8 * scc], &Bs[rb * 64]);
        }
        __syncthreads();

        bf16x8 af[4][2], bfr[3][2];
        #pragma unroll
        for (int mt = 0; mt < 4; ++mt)
            #pragma unroll
            for (int s = 0; s < 2; ++s)
                af[mt][s] = *reinterpret_cast<const bf16x8*>(
                    &As[(wm + 16 * mt + l15) * 64 + 8 * ((4 * s + quad) ^ lx)]);
        #pragma unroll
        for (int nt = 0; nt < 3; ++nt)
            #pragma unroll
            for (int s = 0; s < 2; ++s)
                bfr[nt][s] = *reinterpret_cast<const bf16x8*>(
                    &Bs[(wn + 16 * nt + l15) * 64 + 8 * ((4 * s + quad) ^ lx)]);
        if (vblk) {
            #pragma unroll
            for (int s = 0; s < 2; ++s)
                #pragma unroll
                for (int mt = 0; mt < 4; ++mt)
                    #pragma unroll
                    for (int nt = 0; nt < 3; ++nt)
                        acc[mt][nt] = __builtin_amdgcn_mfma_f32_16x16x32_bf16(
                            bfr[nt][s], af[mt][s], acc[mt][nt], 0, 0, 0);
        } else {
            #pragma unroll
            for (int s = 0; s < 2; ++s)
                #pragma unroll
                for (int mt = 0; mt < 4; ++mt)
                    #pragma unroll
                    for (int nt = 0; nt < 3; ++nt)
                        acc[mt][nt] = __builtin_amdgcn_mfma_f32_16x16x32_bf16(
                            af[mt][s], bfr[nt][s], acc[mt][nt], 0, 0, 0);
        }
    }

    if (vblk) {
        // transposed tile: proj col c = bn+wn+16nt+4quad+r, token n on l15.
        #pragma unroll
        for (int mt = 0; mt < 4; ++mt) {
            #pragma unroll
            for (int nt = 0; nt < 3; ++nt) {
                #pragma unroll
                for (int r = 0; r < 4; ++r) {
                    const int c      = bn + wn + nt * 16 + 4 * quad + r;
                    const int n      = bm + wm + mt * 16 + l15;
                    const int within = c - 2 * kD;
                    const int h = within >> 6;
                    const int d = within & 63;
                    Vt[((size_t)h * kHD + d) * kN + n] = f2b(acc[mt][nt][r]);
                }
            }
        }
        return;
    }

    #pragma unroll
    for (int mt = 0; mt < 4; ++mt) {
        #pragma unroll
        for (int nt = 0; nt < 3; ++nt) {
            #pragma unroll
            for (int r = 0; r < 4; ++r) {
                const int row = bm + wm + mt * 16 + 4 * quad + r;
                const int col = bn + wn + nt * 16 + l15;
                const float v = acc[mt][nt][r];
                const int proj   = col / kD;       // blocks never span projections
                const int within = col - proj * kD;
                const int h = within >> 6;
                const int d = within & 63;
                if (proj == 0) Qh[((size_t)h * kN + row) * kHD + d] = f2b(v * kQScale);
                else           Kh[((size_t)h * kN + row) * kHD + d] = f2b(v);
            }
        }
    }
}

// Output projection: out[4096 x 768] = AO * WoutT^T + bias.
// 64x64 tile, grid (64,12) = 768 blocks = 3/CU. BK=64: 12 windows x 8 MFMAs
// (was 24 windows x 4 -- the most barrier-diluted kernel in the launch).
__global__ __launch_bounds__(256)
void gemm_out(const short* __restrict__ A, const short* __restrict__ BT,
              const float* __restrict__ bias, float* __restrict__ Cout)
{
    const int bm   = blockIdx.x * 64;
    const int bn   = blockIdx.y * 64;
    const int tid  = threadIdx.x;
    const int wave = tid >> 6;
    const int lane = tid & 63;
    const int l15  = lane & 15;
    const int quad = lane >> 4;
    const int lx   = l15 & 7;
    constexpr int K = kD;
    constexpr int N = kD;

    __shared__ alignas(16) short As[64 * 64];    // 8KB
    __shared__ alignas(16) short Bs[64 * 64];    // 8KB

    floatx4 acc[2][2] = {};
    const int wm = (wave >> 1) * 32;
    const int wn = (wave & 1) * 32;

    const int srl = lane >> 3;               // 8 rows (128B) per issue
    const int scc = (lane & 7) ^ srl;        // swizzled source chunk

    for (int k0 = 0; k0 < K; k0 += 64) {
        __syncthreads();
        #pragma unroll
        for (int j = 0; j < 2; ++j) {
            const int rs = 16 * wave + 8 * j;    // 8 issues cover 64 rows (each)
            async_copy16(&A [(size_t)(bm + rs + srl) * K + k0 + 8 * scc], &As[rs * 64]);
            async_copy16(&BT[(size_t)(bn + rs + srl) * K + k0 + 8 * scc], &Bs[rs * 64]);
        }
        __syncthreads();

        bf16x8 af[2][2], bfr[2][2];
        #pragma unroll
        for (int mt = 0; mt < 2; ++mt)
            #pragma unroll
            for (int s = 0; s < 2; ++s)
                af[mt][s] = *reinterpret_cast<const bf16x8*>(
                    &As[(wm + 16 * mt + l15) * 64 + 8 * ((4 * s + quad) ^ lx)]);
        #pragma unroll
        for (int nt = 0; nt < 2; ++nt)
            #pragma unroll
            for (int s = 0; s < 2; ++s)
                bfr[nt][s] = *reinterpret_cast<const bf16x8*>(
                    &Bs[(wn + 16 * nt + l15) * 64 + 8 * ((4 * s + quad) ^ lx)]);
        #pragma unroll
        for (int s = 0; s < 2; ++s)
            #pragma unroll
            for (int mt = 0; mt < 2; ++mt)
                #pragma unroll
                for (int nt = 0; nt < 2; ++nt)
                    acc[mt][nt] = __builtin_amdgcn_mfma_f32_16x16x32_bf16(
                        af[mt][s], bfr[nt][s], acc[mt][nt], 0, 0, 0);
    }

    #pragma unroll
    for (int mt = 0; mt < 2; ++mt)
        #pragma unroll
        for (int nt = 0; nt < 2; ++nt)
            #pragma unroll
            for (int r = 0; r < 4; ++r) {
                const int row = bm + wm + mt * 16 + 4 * quad + r;
                const int col = bn + wn + nt * 16 + l15;
                Cout[(size_t)row * N + col] = acc[mt][nt][r] + bias[col];
            }
}

// Flash attention v6 (unchanged -- best passing: attn ~86-89us).
// Cross-tile software pipeline: each window has independent MFMA and VALU:
//   iter u: PV(u-1)            [MFMA: pa_prev + V(u-1) from old buffer]
//           barrier; stage(u+1) [into old buffer - PV reads already drained]
//           QK(u)              [MFMA from current buffer]
//           exp/pack(u)->pa     [VALU chain, overlaps next window's PV issue]
// v8/v9 lesson: register-widening restructures (PV skew w/ V-in-regs; mt=4)
// both failed correctness without a locatable root cause -- family frozen.
__global__ __launch_bounds__(256)
void attn(const short* __restrict__ Qh, const short* __restrict__ Kh,
          const short* __restrict__ Vt, short* __restrict__ AO)
{
    const int flat = blockIdx.y * 64 + blockIdx.x;    // 0..767
    const int W    = (flat & 7) * 96 + (flat >> 3);   // bijective XCD remap
    const int h    = W >> 6;                          // W / 64
    const int q0   = (W & 63) * 64;

    const int tid  = threadIdx.x;
    const int wave = tid >> 6;          // 0..3
    const int lane = tid & 63;
    const int l15  = lane & 15;
    const int quad = lane >> 4;
    const int lx   = l15 & 7;
    const int wm   = wave >> 1;         // Q-row half owner
    const int wk   = wave & 1;          // KV half owner

    __shared__ alignas(16) short smem[16384];   // Ks[2]:0..8191, Vs[2]:8192..16383
    __shared__ float Dr[2][2][16];              // [wm][mt][4*quad+r] denom partials
    short* Ks0 = smem;
    short* Vs0 = smem + 8192;

    // Q fragments: B-operand of QK^T. qf[mt][s] = Q[q0+32wm+16mt+l15][32s+8quad..)
    bf16x8 qf[2][2];
    {
        const size_t qb = ((size_t)h * kN + q0 + 32 * wm + l15) * kHD;
        #pragma unroll
        for (int mt = 0; mt < 2; ++mt)
            #pragma unroll
            for (int s = 0; s < 2; ++s)
                qf[mt][s] = *reinterpret_cast<const bf16x8*>(
                    &Qh[qb + (size_t)(16 * mt) * kHD + 32 * s + 8 * quad]);
    }

    // all-ones B fragment: mfma(pa, ones) sums each P row -> softmax denom;
    // C-layout puts denom[row=16mt+4quad+r] in reg r of every lane.
    bf16x8 onesf;
    #pragma unroll
    for (int i = 0; i < 8; ++i) onesf[i] = (short)0x3F80;

    floatx4 oacc[2][4] = {};   // [mt][dt]: rows 32wm+16mt+4quad+r, cols 16dt+l15
    floatx4 dacc[2] = {};      // [mt] denom partial (this wave's kv half)

    // staging lane constants: each issue = 8 rows x 128B; physical chunk
    // (lane&7) holds logical chunk (lane&7)^(row&7)  (XOR swizzle)
    const int srl = lane >> 3;              // row within 8-row issue
    const int scc = (lane & 7) ^ srl;       // swizzled source chunk

    // hoisted per-lane staging base pointers (row 16*wave + srl, chunk scc)
    const short* kgp = &Kh[(size_t)h * kN * kHD +
                           (size_t)(16 * wave + srl) * kHD + 8 * scc];
    const short* vgp = &Vt[(size_t)h * kHD * kN +
                           (size_t)(16 * wave + srl) * kN + 8 * scc];
    short* kls = Ks0 + (16 * wave) * 64;    // wave's LDS dst base (K)
    short* vls = Vs0 + (16 * wave) * 64;    // wave's LDS dst base (V)

    auto stage = [&](int b, int kv0) {
        #pragma unroll
        for (int j = 0; j < 2; ++j) {
            async_copy16(kgp + (size_t)(kv0 + 8 * j) * kHD, kls + b * 4096 + (8 * j) * 64);
            async_copy16(vgp + (size_t)(8 * j) * kN + kv0,  vls + b * 4096 + (8 * j) * 64);
        }
    };

    // QK for tile in Kc, then exp/pack into pa (in-register A-fragment).
    auto qk_exp = [&](const short* Kc, bf16x8 (&pa)[2]) {
        floatx4 sacc[2][2] = {};   // [mt][nt]
        __builtin_amdgcn_s_setprio(1);
        #pragma unroll
        for (int nt = 0; nt < 2; ++nt) {
            #pragma unroll
            for (int s = 0; s < 2; ++s) {
                bf16x8 kf = *reinterpret_cast<const bf16x8*>(
                    &Kc[(32 * wk + 16 * nt + l15) * 64 + 8 * ((4 * s + quad) ^ lx)]);
                #pragma unroll
                for (int mt = 0; mt < 2; ++mt)
                    sacc[mt][nt] = __builtin_amdgcn_mfma_f32_16x16x32_bf16(
                        kf, qf[mt][s], sacc[mt][nt], 0, 0, 0);
            }
        }
        __builtin_amdgcn_s_setprio(0);
        // producer lane(l15,q') holds P[m][kv=16nt+4q'+r]; A-frag word algebra:
        // w0=[X0 X2 Y0 Y2], w2=[X1 X3 Y1 Y3] over quads = swap16(swap32(X,Y)).
        #pragma unroll
        for (int mt = 0; mt < 2; ++mt) {
            float e[2][4];
            #pragma unroll
            for (int nt = 0; nt < 2; ++nt)
                #pragma unroll
                for (int r = 0; r < 4; ++r)
                    e[nt][r] = fast_exp2(sacc[mt][nt][r]);
            unsigned x0 = cvt_pk_bf16(e[0][0], e[0][1]);
            unsigned y0 = cvt_pk_bf16(e[1][0], e[1][1]);
            unsigned x1 = cvt_pk_bf16(e[0][2], e[0][3]);
            unsigned y1 = cvt_pk_bf16(e[1][2], e[1][3]);
            permlane32_swap(x0, y0);
            permlane16_swap(x0, y0);
            permlane32_swap(x1, y1);
            permlane16_swap(x1, y1);
            union { uint4v u; bf16x8 v; } pu;
            pu.u[0] = x0; pu.u[1] = x1; pu.u[2] = y0; pu.u[3] = y1;
            pa[mt] = pu.v;
        }
    };

    // PV + denom for the tile whose V lives in Vc, P in pa.
    auto pv = [&](const short* Vc, const bf16x8 (&pa)[2]) {
        __builtin_amdgcn_s_setprio(1);
        #pragma unroll
        for (int dt = 0; dt < 4; ++dt) {
            bf16x8 vv = *reinterpret_cast<const bf16x8*>(
                &Vc[(16 * dt + l15) * 64 + 8 * ((4 * wk + quad) ^ lx)]);
            #pragma unroll
            for (int mt = 0; mt < 2; ++mt)
                oacc[mt][dt] = __builtin_amdgcn_mfma_f32_16x16x32_bf16(
                    pa[mt], vv, oacc[mt][dt], 0, 0, 0);
        }
        #pragma unroll
        for (int mt = 0; mt < 2; ++mt)
            dacc[mt] = __builtin_amdgcn_mfma_f32_16x16x32_bf16(
                pa[mt], onesf, dacc[mt], 0, 0, 0);
        __builtin_amdgcn_s_setprio(0);
    };

    constexpr int kNT = kN / 64;   // 64 tiles
    bf16x8 paA[2], paB[2];

    // tile 0 (no PV yet)
    stage(0, 0);
    __syncthreads();               // stage(0) drained
    stage(1, 64);
    qk_exp(Ks0, paA);
    int cur = 1;

    // tiles 1..62 in pairs (31 pairs); invariant at entry: buf[cur]=tile u,
    // buf[cur^1]=tile u-1, pa holds P(u-1).
    for (int tp = 0; tp < 31; ++tp) {
        const int u = 2 * tp + 1;
        // --- tile u ---
        pv(Vs0 + (cur ^ 1) * 4096, paA);
        __syncthreads();           // PV reads done everywhere; stage(u) drained
        stage(cur ^ 1, (u + 1) * 64);
        qk_exp(Ks0 + cur * 4096, paB);
        cur ^= 1;
        // --- tile u+1 ---
        pv(Vs0 + (cur ^ 1) * 4096, paB);
        __syncthreads();
        stage(cur ^ 1, (u + 2) * 64);
        qk_exp(Ks0 + cur * 4096, paA);
        cur ^= 1;
    }

    // tile 63
    pv(Vs0 + (cur ^ 1) * 4096, paA);
    __syncthreads();               // stage(63) drained
    qk_exp(Ks0 + cur * 4096, paB);
    pv(Vs0 + cur * 4096, paB);     // final PV (no further staging)

    // ---- epilogue: combine wk=0/1 partials (O and denom) ----
    __syncthreads();   // all main-loop LDS reads done; smem reusable
    float* red = reinterpret_cast<float*>(smem);   // 4096 floats = 16KB
    if (wk == 1) {
        #pragma unroll
        for (int mt = 0; mt < 2; ++mt)
            #pragma unroll
            for (int dt = 0; dt < 4; ++dt)
                *reinterpret_cast<floatx4*>(
                    &red[wm * 2048 + (mt * 4 + dt) * 256 + l15 * 16 + quad * 4]) =
                    oacc[mt][dt];
        if (l15 == 0) {
            #pragma unroll
            for (int mt = 0; mt < 2; ++mt)
                #pragma unroll
                for (int r = 0; r < 4; ++r)
                    Dr[wm][mt][4 * quad + r] = dacc[mt][r];
        }
    }
    __syncthreads();
    if (wk == 0) {
        #pragma unroll
        for (int mt = 0; mt < 2; ++mt) {
            #pragma unroll
            for (int dt = 0; dt < 4; ++dt)
                oacc[mt][dt] += *reinterpret_cast<const floatx4*>(
                    &red[wm * 2048 + (mt * 4 + dt) * 256 + l15 * 16 + quad * 4]);
            float inv[4];
            #pragma unroll
            for (int r = 0; r < 4; ++r)
                inv[r] = 1.0f / (dacc[mt][r] + Dr[wm][mt][4 * quad + r]);
            #pragma unroll
            for (int dt = 0; dt < 4; ++dt) {
                #pragma unroll
                for (int r = 0; r < 4; ++r) {
                    const int row = q0 + 32 * wm + 16 * mt + 4 * quad + r;
                    const int col = h * kHD + 16 * dt + l15;
                    AO[(size_t)row * kD + col] = f2b(oacc[mt][dt][r] * inv[r]);
                }
            }
        }
    }
}

extern "C" void kernel_launch(void* const* d_in, const int* in_sizes, int n_in,
                              void* d_out, int out_size, void* d_ws, size_t ws_size,
                              hipStream_t stream)
{
    const float* x     = (const float*)d_in[0];  // (4096, 768) fp32
    const float* W_qkv = (const float*)d_in[1];  // (768, 2304) fp32
    const float* W_out = (const float*)d_in[2];  // (768, 768)  fp32
    const float* b_out = (const float*)d_in[3];  // (768,)      fp32
    float* out = (float*)d_out;                  // (4096, 768) fp32

    const size_t HNHD = (size_t)kH * kN * kHD;   // 3,145,728 shorts per tensor
    short* Qh    = (short*)d_ws;                 // [H][N][64]
    short* Kh    = Qh + HNHD;
    short* Vt    = Kh + HNHD;                    // [H][64][N]
    short* Xb    = Vt + HNHD;                    // x bf16 [N][768]; reused as AO
    short* WqkvT = Xb + (size_t)kN * kD;         // [2304][768]
    short* WoutT = WqkvT + (size_t)k3D * kD;     // [768][768]
    short* AO    = Xb;                           // overlay: Xb dead after QKV gemm
    (void)in_sizes; (void)n_in; (void)out_size; (void)ws_size;

    // 0) fused conversions/transposes (one launch)
    prep<<<dim3(kBlkX + kBlkWq + kBlkWo), dim3(256), 0, stream>>>(
        x, W_qkv, W_out, Xb, WqkvT, WoutT);

    // 1) QKV projection + head scatter (128x96 tiles, BK=64)
    gemm_qkv<<<dim3(kN / 128, k3D / 96), dim3(256), 0, stream>>>(
        Xb, WqkvT, Qh, Kh, Vt);
    // 2) flash attention (v6: 2x2 wave split, cross-tile software pipeline)
    attn<<<dim3(kN / 64, kH), dim3(256), 0, stream>>>(Qh, Kh, Vt, AO);
    // 3) output projection + bias (64x64 tiles, BK=64)
    gemm_out<<<dim3(kN / 64, kD / 64), dim3(256), 0, stream>>>(
        AO, WoutT, b_out, out);
}